// Round 2
// baseline (24597.375 us; speedup 1.0000x reference)
//
#include <hip/hip_runtime.h>
#include <math.h>
#include <stdint.h>

// BiLSTMModel: char-LSTM (GEMM-shaped) -> 2x BiLSTM scans (latency-bound) -> FCs.
// Scans: 32 WGs x 512 thr per direction, W_hh fp32 in VGPRs, h exchanged via
// 2-slot LLC-resident ring of tagged 8B words {fp32 h, u32 tag}.

#define NPOS 4096
#define GDIM 2048   // 4*H

typedef unsigned int uint4v __attribute__((ext_vector_type(4)));

__device__ __forceinline__ float sigf(float x) { return 1.0f / (1.0f + __expf(-x)); }
__device__ __forceinline__ float tanh_fast(float x) {
  float e = __expf(2.f * x);
  return 1.f - 2.f / (e + 1.f);   // exact at +-inf, NaN-free
}

// ---------------- build transposed concat char weight: Wt[k][g]
__global__ __launch_bounds__(256) void build_wt_kernel(
    const float* __restrict__ cWih, const float* __restrict__ cWhh,
    float* __restrict__ Wt)
{
  __shared__ float tile[64][65];
  const int k0 = blockIdx.x * 64;
  const int g0 = blockIdx.y * 64;
  const float* src = (k0 < 256) ? cWih : cWhh;
  const int sk0 = k0 & 255;
  for (int i = threadIdx.x; i < 64 * 64; i += 256) {
    int r = i >> 6, cc = i & 63;
    tile[r][cc] = src[(size_t)(g0 + r) * 256 + sk0 + cc];
  }
  __syncthreads();
  for (int i = threadIdx.x; i < 64 * 64; i += 256) {
    int kk = i >> 6, gg = i & 63;
    Wt[(size_t)(k0 + kk) * 1024 + g0 + gg] = tile[gg][kk];
  }
}

// ---------------- char LSTM: 256 blocks x 16 words, thread = channel
__global__ __launch_bounds__(256) void char_lstm_kernel(
    const int* __restrict__ chars, const int* __restrict__ lens,
    const float* __restrict__ table, const float* __restrict__ Wt,
    const float* __restrict__ cb, float* __restrict__ word_emb)
{
  __shared__ float u[16][512];
  __shared__ float wt[8][1024];
  __shared__ int sidx[16];
  const int tid = threadIdx.x;
  const int ch = tid;
  const int w0 = blockIdx.x * 16;
  if (tid < 16) { int l = lens[w0 + tid]; sidx[tid] = (l < 1 ? 1 : l) - 1; }
  float c[16], acc0[16], acc1[16], acc2[16], acc3[16];
  #pragma unroll
  for (int w = 0; w < 16; ++w) { u[w][256 + ch] = 0.f; c[w] = 0.f; }
  const float cb0 = cb[ch], cb1 = cb[256 + ch], cb2 = cb[512 + ch], cb3 = cb[768 + ch];

  for (int t = 0; t < 16; ++t) {
    for (int w = 0; w < 16; ++w) {
      int cid = chars[(w0 + w) * 16 + t];
      u[w][ch] = table[(size_t)cid * 256 + ch];
    }
    #pragma unroll
    for (int w = 0; w < 16; ++w) { acc0[w] = cb0; acc1[w] = cb1; acc2[w] = cb2; acc3[w] = cb3; }
    for (int k0 = 0; k0 < 512; k0 += 8) {
      #pragma unroll
      for (int r = 0; r < 8; ++r)
        ((float4*)&wt[r][0])[tid] = ((const float4*)(Wt + (size_t)(k0 + r) * 1024))[tid];
      __syncthreads();
      #pragma unroll
      for (int kk = 0; kk < 8; ++kk) {
        const float wv0 = wt[kk][ch], wv1 = wt[kk][256 + ch];
        const float wv2 = wt[kk][512 + ch], wv3 = wt[kk][768 + ch];
        #pragma unroll
        for (int w = 0; w < 16; ++w) {
          const float uv = u[w][k0 + kk];
          acc0[w] = fmaf(wv0, uv, acc0[w]);
          acc1[w] = fmaf(wv1, uv, acc1[w]);
          acc2[w] = fmaf(wv2, uv, acc2[w]);
          acc3[w] = fmaf(wv3, uv, acc3[w]);
        }
      }
      __syncthreads();
    }
    #pragma unroll
    for (int w = 0; w < 16; ++w) {
      float iv = sigf(acc0[w]), fv = sigf(acc1[w]);
      float gv = tanhf(acc2[w]), ov = sigf(acc3[w]);
      c[w] = fv * c[w] + iv * gv;
      float h = ov * tanhf(c[w]);
      u[w][256 + ch] = h;
      if (t == sidx[w]) word_emb[(size_t)(w0 + w) * 256 + ch] = h;
    }
  }
}

// ---------------- generic fp32 GEMM: C = act(A @ B^T + bias)
template <int SPLIT, int ACT>
__global__ __launch_bounds__(256) void gemm_kernel(
    const float* __restrict__ A, const float* __restrict__ A2,
    const float* __restrict__ B, const float* __restrict__ bias,
    float* __restrict__ C, int M, int N, int K)
{
  __shared__ float At[8][132];
  __shared__ float Bt[8][132];
  const int tid = threadIdx.x;
  const int bm0 = blockIdx.x * 128, bn0 = blockIdx.y * 128;
  float acc[8][8];
  #pragma unroll
  for (int i = 0; i < 8; ++i)
    #pragma unroll
    for (int j = 0; j < 8; ++j) acc[i][j] = 0.f;
  const int sr = tid >> 1;
  const int sk = (tid & 1) * 4;
  const int tm = (tid >> 4) * 8, tn = (tid & 15) * 8;
  for (int k0 = 0; k0 < K; k0 += 8) {
    const int kg = k0 + sk;
    float4 av;
    if (SPLIT) {
      const float* srcp = (kg < 512) ? A : A2;
      av = *(const float4*)(srcp + (size_t)(bm0 + sr) * 512 + (kg & 511));
    } else {
      av = *(const float4*)(A + (size_t)(bm0 + sr) * K + kg);
    }
    float4 bv = {0.f, 0.f, 0.f, 0.f};
    if (bn0 + sr < N) bv = *(const float4*)(B + (size_t)(bn0 + sr) * K + kg);
    At[sk + 0][sr] = av.x; At[sk + 1][sr] = av.y; At[sk + 2][sr] = av.z; At[sk + 3][sr] = av.w;
    Bt[sk + 0][sr] = bv.x; Bt[sk + 1][sr] = bv.y; Bt[sk + 2][sr] = bv.z; Bt[sk + 3][sr] = bv.w;
    __syncthreads();
    #pragma unroll
    for (int kk = 0; kk < 8; ++kk) {
      float a[8], b[8];
      *(float4*)&a[0] = *(const float4*)&At[kk][tm];
      *(float4*)&a[4] = *(const float4*)&At[kk][tm + 4];
      *(float4*)&b[0] = *(const float4*)&Bt[kk][tn];
      *(float4*)&b[4] = *(const float4*)&Bt[kk][tn + 4];
      #pragma unroll
      for (int i = 0; i < 8; ++i)
        #pragma unroll
        for (int j = 0; j < 8; ++j) acc[i][j] = fmaf(a[i], b[j], acc[i][j]);
    }
    __syncthreads();
  }
  #pragma unroll
  for (int i = 0; i < 8; ++i) {
    const int m = bm0 + tm + i;
    float* crow = C + (size_t)m * N;
    #pragma unroll
    for (int j = 0; j < 8; ++j) {
      const int n = bn0 + tn + j;
      if (n < N) {
        float v = acc[i][j] + bias[n];
        if (ACT) v = tanhf(v);
        crow[n] = v;
      }
    }
  }
}

// ---------------- persistent bidirectional scan, 2-slot LLC ring
// grid = 64 blocks x 512 thr: dir = bid>>5, wg = bid&31 (16 hidden units/WG).
// row8 = tid>>3 = u*4+g (u in 0..15, g in 0..3), klane = tid&7 (64-wide k chunk).
// Roles per 32-thread group: lane 0 = leader (state+stores), lanes 1-4 = X
// prefetchers, lanes 16-31 = pollers (one 16B coherent load each, nothing else
// in their vmcnt queue). T ring: slot s&1 holds h of step s tagged s+1.
__global__ __launch_bounds__(512) void scan_kernel(
    const float* __restrict__ Xf, const float* __restrict__ Xb,
    const float* __restrict__ Whf, const float* __restrict__ Whb,
    unsigned long long* __restrict__ Tf, unsigned long long* __restrict__ Tb,
    float* __restrict__ Hf, float* __restrict__ Hb)
{
  __shared__ float lds_h[2][528];   // padded: logical j at j + (j>>5)
  __shared__ float xlds[2][64];     // staged x2h value per row
  const int tid = threadIdx.x;
  const int dir = blockIdx.x >> 5;
  const int wg  = blockIdx.x & 31;
  const float* X = dir ? Xb : Xf;
  const float* Wh = dir ? Whb : Whf;
  unsigned long long* T = dir ? Tb : Tf;
  float* Hd = dir ? Hb : Hf;

  const int row8 = tid >> 3;              // 0..63
  const int klane = tid & 7;
  const int u = row8 >> 2, g = row8 & 3;
  const int R = g * 512 + wg * 16 + u;    // gate-major row in [0,2048)

  const int sub = tid & 31;
  const bool isLeader = (sub == 0);
  const bool isPoller = (sub >= 16);
  const int prank = (tid >> 5) * 16 + (sub - 16);   // 0..255
  const bool isPref = (sub >= 1 && sub <= 4);
  const int prefr = (tid >> 5) * 4 + (sub - 1);     // 0..63
  const int Rp = (prefr & 3) * 512 + wg * 16 + (prefr >> 2);

  float wreg[64];
  {
    const float* wrow = Wh + (size_t)R * 512 + klane * 64;
    #pragma unroll
    for (int i = 0; i < 16; ++i) {
      float4 v = ((const float4*)wrow)[i];
      wreg[4 * i] = v.x; wreg[4 * i + 1] = v.y; wreg[4 * i + 2] = v.z; wreg[4 * i + 3] = v.w;
    }
  }
  const int l0 = klane * 66;     // padded base of k-chunk [klane*64, +32)
  const int l1 = l0 + 33;        // padded base of [+32, +64)
  const int j0 = 2 * prank;
  const int la = j0 + (j0 >> 5);

  for (int i = tid; i < 528; i += 512) lds_h[0][i] = 0.f;
  float regA = 0.f, regB = 0.f;
  if (isPref) {
    xlds[0][prefr] = X[(size_t)(dir ? NPOS - 1 : 0) * GDIM + Rp];
    regA = X[(size_t)(dir ? NPOS - 2 : 1) * GDIM + Rp];
  }
  float creg = 0.f;
  bool fb = false;
  __syncthreads();

  auto step = [&](int s, float& cur, float& nxt) {
    const int p = dir ? (NPOS - 1 - s) : s;
    if (s > 0 && isPoller) {
      const unsigned int tg = (unsigned int)s;
      const unsigned long long* srcp = T + (size_t)((s - 1) & 1) * 512 + j0;
      float h0, h1;
      if (!fb) {
        uint4v q;
        asm volatile("global_load_dwordx4 %0, %1, off sc0 sc1\n\ts_waitcnt vmcnt(0)"
                     : "=v"(q) : "v"(srcp) : "memory");
        int spins = 0;
        while (q.y != tg || q.w != tg) {
          if (++spins > 16384) { fb = true; break; }
          asm volatile("global_load_dwordx4 %0, %1, off sc0 sc1\n\ts_waitcnt vmcnt(0)"
                       : "=v"(q) : "v"(srcp) : "memory");
        }
        h0 = __uint_as_float(q.x); h1 = __uint_as_float(q.z);
      }
      if (fb) {   // guaranteed-correct fallback (sticky)
        unsigned long long v0, v1;
        do { v0 = __hip_atomic_load(srcp, __ATOMIC_RELAXED, __HIP_MEMORY_SCOPE_AGENT); }
        while ((unsigned int)(v0 >> 32) != tg);
        do { v1 = __hip_atomic_load(srcp + 1, __ATOMIC_RELAXED, __HIP_MEMORY_SCOPE_AGENT); }
        while ((unsigned int)(v1 >> 32) != tg);
        h0 = __uint_as_float((unsigned int)v0);
        h1 = __uint_as_float((unsigned int)v1);
      }
      lds_h[s & 1][la] = h0;
      lds_h[s & 1][la + 1] = h1;
    }
    if (isPref && s + 2 < NPOS) {
      const int p2 = dir ? (NPOS - 3 - s) : (s + 2);
      nxt = X[(size_t)p2 * GDIM + Rp];
    }
    __syncthreads();
    if (isPref) xlds[(s + 1) & 1][prefr] = cur;   // value for step s+1 (loaded 2 steps ago)
    const float* hb = &lds_h[s & 1][0];
    float sum = (klane == 0) ? xlds[s & 1][row8] : 0.f;
    #pragma unroll
    for (int i = 0; i < 32; ++i) sum = fmaf(wreg[i], hb[l0 + i], sum);
    #pragma unroll
    for (int i = 0; i < 32; ++i) sum = fmaf(wreg[32 + i], hb[l1 + i], sum);
    sum += __shfl_xor(sum, 1);
    sum += __shfl_xor(sum, 2);
    sum += __shfl_xor(sum, 4);
    const int base = (tid & 63) & ~31;   // lane base of this unit's 32-group
    float gf = __shfl(sum, base + 8);
    float gg = __shfl(sum, base + 16);
    float go = __shfl(sum, base + 24);
    if (isLeader) {
      float iv = sigf(sum), fv = sigf(gf), gv = tanh_fast(gg), ov = sigf(go);
      creg = fv * creg + iv * gv;
      float h = ov * tanh_fast(creg);
      const int j = wg * 16 + u;
      unsigned long long pack = ((unsigned long long)(unsigned int)(s + 1) << 32)
                              | (unsigned long long)__float_as_uint(h);
      __hip_atomic_store(&T[(size_t)(s & 1) * 512 + j], pack,
                         __ATOMIC_RELAXED, __HIP_MEMORY_SCOPE_AGENT);
      Hd[(size_t)p * 512 + j] = h;
    }
  };

  for (int s = 0; s < NPOS; s += 2) {
    step(s, regA, regB);
    step(s + 1, regB, regA);
  }
}

extern "C" void kernel_launch(void* const* d_in, const int* in_sizes, int n_in,
                              void* d_out, int out_size, void* d_ws, size_t ws_size,
                              hipStream_t stream) {
  const int* chars = (const int*)d_in[0];
  const int* lens = (const int*)d_in[1];
  const float* table = (const float*)d_in[2];
  const float* cWih = (const float*)d_in[3];
  const float* cWhh = (const float*)d_in[4];
  const float* cb = (const float*)d_in[5];
  const float* Wih0 = (const float*)d_in[6];   // [2][2048][256]
  const float* Whh0 = (const float*)d_in[7];   // [2][2048][512]
  const float* b0 = (const float*)d_in[8];
  const float* Wih1 = (const float*)d_in[9];   // [2][2048][1024]
  const float* Whh1 = (const float*)d_in[10];  // [2][2048][512]
  const float* b1 = (const float*)d_in[11];
  const float* fc1w = (const float*)d_in[12];
  const float* fc1b = (const float*)d_in[13];
  const float* fc2w = (const float*)d_in[14];
  const float* fc2b = (const float*)d_in[15];
  float* out = (float*)d_out;

  char* ws = (char*)d_ws;
  size_t off = 0;
  auto alloc = [&](size_t bytes) -> void* {
    void* p = ws + off;
    off += (bytes + 255) & ~(size_t)255;
    return p;
  };
  float* word_emb = (float*)alloc((size_t)4096 * 256 * 4);
  float* X0f = (float*)alloc((size_t)4096 * 2048 * 4);
  float* X0b = (float*)alloc((size_t)4096 * 2048 * 4);
  float* H0f = (float*)alloc((size_t)4096 * 512 * 4);
  float* H0b = (float*)alloc((size_t)4096 * 512 * 4);
  float* H1f = (float*)alloc((size_t)4096 * 512 * 4);
  float* H1b = (float*)alloc((size_t)4096 * 512 * 4);
  float* fc1out = (float*)alloc((size_t)4096 * 512 * 4);
  float* Wt = (float*)alloc((size_t)512 * 1024 * 4);
  unsigned long long* Tall = (unsigned long long*)alloc((size_t)4 * 1024 * 8);  // 4 rings x 2 slots x 512
  unsigned long long* T0f = Tall;
  unsigned long long* T0b = Tall + 1024;
  unsigned long long* T1f = Tall + 2048;
  unsigned long long* T1b = Tall + 3072;
  if (off > ws_size) return;

  // clear tag rings (inside graph -> every replay re-synchronizes honestly)
  hipMemsetAsync(Tall, 0, (size_t)4 * 1024 * 8, stream);

  build_wt_kernel<<<dim3(8, 16), 256, 0, stream>>>(cWih, cWhh, Wt);
  char_lstm_kernel<<<256, 256, 0, stream>>>(chars, lens, table, Wt, cb, word_emb);

  gemm_kernel<0, 0><<<dim3(32, 16), 256, 0, stream>>>(
      word_emb, nullptr, Wih0, b0, X0f, 4096, 2048, 256);
  gemm_kernel<0, 0><<<dim3(32, 16), 256, 0, stream>>>(
      word_emb, nullptr, Wih0 + (size_t)2048 * 256, b0 + 2048, X0b, 4096, 2048, 256);
  scan_kernel<<<64, 512, 0, stream>>>(X0f, X0b, Whh0, Whh0 + (size_t)2048 * 512,
                                      T0f, T0b, H0f, H0b);

  gemm_kernel<1, 0><<<dim3(32, 16), 256, 0, stream>>>(
      H0f, H0b, Wih1, b1, X0f, 4096, 2048, 1024);
  gemm_kernel<1, 0><<<dim3(32, 16), 256, 0, stream>>>(
      H0f, H0b, Wih1 + (size_t)2048 * 1024, b1 + 2048, X0b, 4096, 2048, 1024);
  scan_kernel<<<64, 512, 0, stream>>>(X0f, X0b, Whh1, Whh1 + (size_t)2048 * 512,
                                      T1f, T1b, H1f, H1b);

  gemm_kernel<1, 1><<<dim3(32, 4), 256, 0, stream>>>(
      H1f, H1b, fc1w, fc1b, fc1out, 4096, 512, 1024);
  gemm_kernel<0, 0><<<dim3(32, 1), 256, 0, stream>>>(
      fc1out, nullptr, fc2w, fc2b, out, 4096, 50, 512);
}

// Round 3
// 16684.018 us; speedup vs baseline: 1.4743x; 1.4743x over previous
//
#include <hip/hip_runtime.h>
#include <math.h>
#include <stdint.h>

// BiLSTMModel: char-LSTM (GEMM-shaped) -> 2x BiLSTM scans (latency-bound) -> FCs.
// Scan v3: 32 WGs x 512 thr per direction. W_hh fp32 in VGPRs. h exchanged via
// 2-slot LLC-resident ring of tagged 8B words {fp32 h, u32 tag}; every thread
// polls exactly ONE word with a plain relaxed agent-scope atomic load.

#define NPOS 4096
#define GDIM 2048   // 4*H

__device__ __forceinline__ float sigf(float x) { return 1.0f / (1.0f + __expf(-x)); }
__device__ __forceinline__ float tanh_fast(float x) {
  float e = __expf(2.f * x);
  return 1.f - 2.f / (e + 1.f);   // exact at +-inf, NaN-free
}

// ---------------- build transposed concat char weight: Wt[k][g]
__global__ __launch_bounds__(256) void build_wt_kernel(
    const float* __restrict__ cWih, const float* __restrict__ cWhh,
    float* __restrict__ Wt)
{
  __shared__ float tile[64][65];
  const int k0 = blockIdx.x * 64;
  const int g0 = blockIdx.y * 64;
  const float* src = (k0 < 256) ? cWih : cWhh;
  const int sk0 = k0 & 255;
  for (int i = threadIdx.x; i < 64 * 64; i += 256) {
    int r = i >> 6, cc = i & 63;
    tile[r][cc] = src[(size_t)(g0 + r) * 256 + sk0 + cc];
  }
  __syncthreads();
  for (int i = threadIdx.x; i < 64 * 64; i += 256) {
    int kk = i >> 6, gg = i & 63;
    Wt[(size_t)(k0 + kk) * 1024 + g0 + gg] = tile[gg][kk];
  }
}

// ---------------- char LSTM: 256 blocks x 16 words, thread = channel
__global__ __launch_bounds__(256) void char_lstm_kernel(
    const int* __restrict__ chars, const int* __restrict__ lens,
    const float* __restrict__ table, const float* __restrict__ Wt,
    const float* __restrict__ cb, float* __restrict__ word_emb)
{
  __shared__ float u[16][512];
  __shared__ float wt[8][1024];
  __shared__ int sidx[16];
  const int tid = threadIdx.x;
  const int ch = tid;
  const int w0 = blockIdx.x * 16;
  if (tid < 16) { int l = lens[w0 + tid]; sidx[tid] = (l < 1 ? 1 : l) - 1; }
  float c[16], acc0[16], acc1[16], acc2[16], acc3[16];
  #pragma unroll
  for (int w = 0; w < 16; ++w) { u[w][256 + ch] = 0.f; c[w] = 0.f; }
  const float cb0 = cb[ch], cb1 = cb[256 + ch], cb2 = cb[512 + ch], cb3 = cb[768 + ch];

  for (int t = 0; t < 16; ++t) {
    for (int w = 0; w < 16; ++w) {
      int cid = chars[(w0 + w) * 16 + t];
      u[w][ch] = table[(size_t)cid * 256 + ch];
    }
    #pragma unroll
    for (int w = 0; w < 16; ++w) { acc0[w] = cb0; acc1[w] = cb1; acc2[w] = cb2; acc3[w] = cb3; }
    for (int k0 = 0; k0 < 512; k0 += 8) {
      #pragma unroll
      for (int r = 0; r < 8; ++r)
        ((float4*)&wt[r][0])[tid] = ((const float4*)(Wt + (size_t)(k0 + r) * 1024))[tid];
      __syncthreads();
      #pragma unroll
      for (int kk = 0; kk < 8; ++kk) {
        const float wv0 = wt[kk][ch], wv1 = wt[kk][256 + ch];
        const float wv2 = wt[kk][512 + ch], wv3 = wt[kk][768 + ch];
        #pragma unroll
        for (int w = 0; w < 16; ++w) {
          const float uv = u[w][k0 + kk];
          acc0[w] = fmaf(wv0, uv, acc0[w]);
          acc1[w] = fmaf(wv1, uv, acc1[w]);
          acc2[w] = fmaf(wv2, uv, acc2[w]);
          acc3[w] = fmaf(wv3, uv, acc3[w]);
        }
      }
      __syncthreads();
    }
    #pragma unroll
    for (int w = 0; w < 16; ++w) {
      float iv = sigf(acc0[w]), fv = sigf(acc1[w]);
      float gv = tanhf(acc2[w]), ov = sigf(acc3[w]);
      c[w] = fv * c[w] + iv * gv;
      float h = ov * tanhf(c[w]);
      u[w][256 + ch] = h;
      if (t == sidx[w]) word_emb[(size_t)(w0 + w) * 256 + ch] = h;
    }
  }
}

// ---------------- generic fp32 GEMM: C = act(A @ B^T + bias)
template <int SPLIT, int ACT>
__global__ __launch_bounds__(256) void gemm_kernel(
    const float* __restrict__ A, const float* __restrict__ A2,
    const float* __restrict__ B, const float* __restrict__ bias,
    float* __restrict__ C, int M, int N, int K)
{
  __shared__ float At[8][132];
  __shared__ float Bt[8][132];
  const int tid = threadIdx.x;
  const int bm0 = blockIdx.x * 128, bn0 = blockIdx.y * 128;
  float acc[8][8];
  #pragma unroll
  for (int i = 0; i < 8; ++i)
    #pragma unroll
    for (int j = 0; j < 8; ++j) acc[i][j] = 0.f;
  const int sr = tid >> 1;
  const int sk = (tid & 1) * 4;
  const int tm = (tid >> 4) * 8, tn = (tid & 15) * 8;
  for (int k0 = 0; k0 < K; k0 += 8) {
    const int kg = k0 + sk;
    float4 av;
    if (SPLIT) {
      const float* srcp = (kg < 512) ? A : A2;
      av = *(const float4*)(srcp + (size_t)(bm0 + sr) * 512 + (kg & 511));
    } else {
      av = *(const float4*)(A + (size_t)(bm0 + sr) * K + kg);
    }
    float4 bv = {0.f, 0.f, 0.f, 0.f};
    if (bn0 + sr < N) bv = *(const float4*)(B + (size_t)(bn0 + sr) * K + kg);
    At[sk + 0][sr] = av.x; At[sk + 1][sr] = av.y; At[sk + 2][sr] = av.z; At[sk + 3][sr] = av.w;
    Bt[sk + 0][sr] = bv.x; Bt[sk + 1][sr] = bv.y; Bt[sk + 2][sr] = bv.z; Bt[sk + 3][sr] = bv.w;
    __syncthreads();
    #pragma unroll
    for (int kk = 0; kk < 8; ++kk) {
      float a[8], b[8];
      *(float4*)&a[0] = *(const float4*)&At[kk][tm];
      *(float4*)&a[4] = *(const float4*)&At[kk][tm + 4];
      *(float4*)&b[0] = *(const float4*)&Bt[kk][tn];
      *(float4*)&b[4] = *(const float4*)&Bt[kk][tn + 4];
      #pragma unroll
      for (int i = 0; i < 8; ++i)
        #pragma unroll
        for (int j = 0; j < 8; ++j) acc[i][j] = fmaf(a[i], b[j], acc[i][j]);
    }
    __syncthreads();
  }
  #pragma unroll
  for (int i = 0; i < 8; ++i) {
    const int m = bm0 + tm + i;
    float* crow = C + (size_t)m * N;
    #pragma unroll
    for (int j = 0; j < 8; ++j) {
      const int n = bn0 + tn + j;
      if (n < N) {
        float v = acc[i][j] + bias[n];
        if (ACT) v = tanhf(v);
        crow[n] = v;
      }
    }
  }
}

// ---------------- persistent bidirectional scan v3
// grid = 64 blocks x 512 thr: dir = bid&1, wg = bid>>1 (16 hidden units/WG).
// row8 = tid>>3 = u*4+g (u 0..15, g 0..3), klane = tid&7 (64-wide k chunk).
// Every thread polls T word [tid] (2-slot ring, tag = step+1), writes it to
// LDS, one barrier, then 64 FMAs + klane shuffle-reduce; 16 leaders do the
// nonlinearity and publish {h, tag} as one 8B word. klane0 threads keep a
// 2-deep register pipeline of their own x2h value.
__global__ __launch_bounds__(512) void scan_kernel(
    const float* __restrict__ Xf, const float* __restrict__ Xb,
    const float* __restrict__ Whf, const float* __restrict__ Whb,
    unsigned long long* __restrict__ Tf, unsigned long long* __restrict__ Tb,
    float* __restrict__ Hf, float* __restrict__ Hb)
{
  __shared__ float lds_h[2][576];   // logical j at j + (j>>5)*4  (16B-aligned chunks)
  const int tid = threadIdx.x;
  const int dir = blockIdx.x & 1;
  const int wg  = blockIdx.x >> 1;
  const float* X = dir ? Xb : Xf;
  const float* Wh = dir ? Whb : Whf;
  unsigned long long* T = dir ? Tb : Tf;
  float* Hd = dir ? Hb : Hf;

  const int row8 = tid >> 3;              // 0..63
  const int klane = tid & 7;
  const int u = row8 >> 2, g = row8 & 3;
  const int R = g * 512 + wg * 16 + u;    // gate-major row in [0,2048)

  float wreg[64];
  {
    const float* wrow = Wh + (size_t)R * 512 + klane * 64;
    #pragma unroll
    for (int i = 0; i < 16; ++i) {
      float4 v = ((const float4*)wrow)[i];
      wreg[4 * i] = v.x; wreg[4 * i + 1] = v.y; wreg[4 * i + 2] = v.z; wreg[4 * i + 3] = v.w;
    }
  }
  const int l0 = 72 * klane;       // padded base of logical [klane*64, +32)
  const int l1 = l0 + 36;          // padded base of logical [klane*64+32, +32)
  const int la = tid + ((tid >> 5) << 2);   // padded slot of logical word tid

  for (int i = tid; i < 576; i += 512) lds_h[0][i] = 0.f;

  const bool xl = (klane == 0);
  float xcur = 0.f, xnxt = 0.f;
  if (xl) {
    xcur = X[(size_t)(dir ? NPOS - 1 : 0) * GDIM + R];
    xnxt = X[(size_t)(dir ? NPOS - 2 : 1) * GDIM + R];
  }
  float creg = 0.f;
  __syncthreads();

  for (int s = 0; s < NPOS; ++s) {
    const int p = dir ? (NPOS - 1 - s) : s;
    if (s > 0) {
      const unsigned int tg = (unsigned int)s;
      const unsigned long long* w = T + (size_t)((s - 1) & 1) * 512 + tid;
      unsigned long long v;
      do { v = __hip_atomic_load(w, __ATOMIC_RELAXED, __HIP_MEMORY_SCOPE_AGENT); }
      while ((unsigned int)(v >> 32) != tg);
      lds_h[s & 1][la] = __uint_as_float((unsigned int)v);
    }
    __syncthreads();
    const float* hb = &lds_h[s & 1][0];
    float sum = xl ? xcur : 0.f;
    if (xl) {   // shift x pipeline; load for step s+2 (consumed in ~2 us)
      xcur = xnxt;
      if (s + 2 < NPOS) xnxt = X[(size_t)(dir ? NPOS - 3 - s : s + 2) * GDIM + R];
    }
    #pragma unroll
    for (int i = 0; i < 8; ++i) {
      float4 a = *(const float4*)&hb[l0 + 4 * i];
      sum = fmaf(wreg[4 * i + 0], a.x, sum);
      sum = fmaf(wreg[4 * i + 1], a.y, sum);
      sum = fmaf(wreg[4 * i + 2], a.z, sum);
      sum = fmaf(wreg[4 * i + 3], a.w, sum);
    }
    #pragma unroll
    for (int i = 0; i < 8; ++i) {
      float4 a = *(const float4*)&hb[l1 + 4 * i];
      sum = fmaf(wreg[32 + 4 * i + 0], a.x, sum);
      sum = fmaf(wreg[32 + 4 * i + 1], a.y, sum);
      sum = fmaf(wreg[32 + 4 * i + 2], a.z, sum);
      sum = fmaf(wreg[32 + 4 * i + 3], a.w, sum);
    }
    sum += __shfl_xor(sum, 1);
    sum += __shfl_xor(sum, 2);
    sum += __shfl_xor(sum, 4);
    const int base = (tid & 63) & ~31;   // this unit's lane base within the wave
    float gf = __shfl(sum, base + 8);
    float gg = __shfl(sum, base + 16);
    float go = __shfl(sum, base + 24);
    if ((tid & 31) == 0) {               // leader: lane base (holds i-gate in sum)
      float iv = sigf(sum), fv = sigf(gf), gv = tanh_fast(gg), ov = sigf(go);
      creg = fv * creg + iv * gv;
      float h = ov * tanh_fast(creg);
      const int j = wg * 16 + u;
      unsigned long long pack = ((unsigned long long)(unsigned int)(s + 1) << 32)
                              | (unsigned long long)__float_as_uint(h);
      __hip_atomic_store(&T[(size_t)(s & 1) * 512 + j], pack,
                         __ATOMIC_RELAXED, __HIP_MEMORY_SCOPE_AGENT);
      Hd[(size_t)p * 512 + j] = h;
    }
  }
}

extern "C" void kernel_launch(void* const* d_in, const int* in_sizes, int n_in,
                              void* d_out, int out_size, void* d_ws, size_t ws_size,
                              hipStream_t stream) {
  const int* chars = (const int*)d_in[0];
  const int* lens = (const int*)d_in[1];
  const float* table = (const float*)d_in[2];
  const float* cWih = (const float*)d_in[3];
  const float* cWhh = (const float*)d_in[4];
  const float* cb = (const float*)d_in[5];
  const float* Wih0 = (const float*)d_in[6];   // [2][2048][256]
  const float* Whh0 = (const float*)d_in[7];   // [2][2048][512]
  const float* b0 = (const float*)d_in[8];
  const float* Wih1 = (const float*)d_in[9];   // [2][2048][1024]
  const float* Whh1 = (const float*)d_in[10];  // [2][2048][512]
  const float* b1 = (const float*)d_in[11];
  const float* fc1w = (const float*)d_in[12];
  const float* fc1b = (const float*)d_in[13];
  const float* fc2w = (const float*)d_in[14];
  const float* fc2b = (const float*)d_in[15];
  float* out = (float*)d_out;

  char* ws = (char*)d_ws;
  size_t off = 0;
  auto alloc = [&](size_t bytes) -> void* {
    void* p = ws + off;
    off += (bytes + 255) & ~(size_t)255;
    return p;
  };
  float* word_emb = (float*)alloc((size_t)4096 * 256 * 4);
  float* X0f = (float*)alloc((size_t)4096 * 2048 * 4);
  float* X0b = (float*)alloc((size_t)4096 * 2048 * 4);
  float* H0f = (float*)alloc((size_t)4096 * 512 * 4);
  float* H0b = (float*)alloc((size_t)4096 * 512 * 4);
  float* H1f = (float*)alloc((size_t)4096 * 512 * 4);
  float* H1b = (float*)alloc((size_t)4096 * 512 * 4);
  float* fc1out = (float*)alloc((size_t)4096 * 512 * 4);
  float* Wt = (float*)alloc((size_t)512 * 1024 * 4);
  unsigned long long* Tall = (unsigned long long*)alloc((size_t)4 * 1024 * 8);  // 4 rings x 2 slots x 512
  unsigned long long* T0f = Tall;
  unsigned long long* T0b = Tall + 1024;
  unsigned long long* T1f = Tall + 2048;
  unsigned long long* T1b = Tall + 3072;
  if (off > ws_size) return;

  // clear tag rings (inside graph -> every replay re-synchronizes honestly)
  hipMemsetAsync(Tall, 0, (size_t)4 * 1024 * 8, stream);

  build_wt_kernel<<<dim3(8, 16), 256, 0, stream>>>(cWih, cWhh, Wt);
  char_lstm_kernel<<<256, 256, 0, stream>>>(chars, lens, table, Wt, cb, word_emb);

  gemm_kernel<0, 0><<<dim3(32, 16), 256, 0, stream>>>(
      word_emb, nullptr, Wih0, b0, X0f, 4096, 2048, 256);
  gemm_kernel<0, 0><<<dim3(32, 16), 256, 0, stream>>>(
      word_emb, nullptr, Wih0 + (size_t)2048 * 256, b0 + 2048, X0b, 4096, 2048, 256);
  scan_kernel<<<64, 512, 0, stream>>>(X0f, X0b, Whh0, Whh0 + (size_t)2048 * 512,
                                      T0f, T0b, H0f, H0b);

  gemm_kernel<1, 0><<<dim3(32, 16), 256, 0, stream>>>(
      H0f, H0b, Wih1, b1, X0f, 4096, 2048, 1024);
  gemm_kernel<1, 0><<<dim3(32, 16), 256, 0, stream>>>(
      H0f, H0b, Wih1 + (size_t)2048 * 1024, b1 + 2048, X0b, 4096, 2048, 1024);
  scan_kernel<<<64, 512, 0, stream>>>(X0f, X0b, Whh1, Whh1 + (size_t)2048 * 512,
                                      T1f, T1b, H1f, H1b);

  gemm_kernel<1, 1><<<dim3(32, 4), 256, 0, stream>>>(
      H1f, H1b, fc1w, fc1b, fc1out, 4096, 512, 1024);
  gemm_kernel<0, 0><<<dim3(32, 1), 256, 0, stream>>>(
      fc1out, nullptr, fc2w, fc2b, out, 4096, 50, 512);
}